// Round 1
// baseline (164.372 us; speedup 1.0000x reference)
//
#include <hip/hip_runtime.h>
#include <math.h>

#define BATCH 128
#define NNODE 512
#define RU 64
#define IN_PER_NODE 2
#define MEM_DIM 16
#define BOT_DIM 4
#define IN_SZ 66            // IN_PER_NODE + RU
#define OUT_SZ 256          // 4*RU
#define HID (NNODE*RU)      // 32768
#define W3_ROW 16896        // IN_SZ*OUT_SZ

__device__ __forceinline__ float sigmoidf_(float x) {
    return 1.0f / (1.0f + __expf(-x));
}

__global__ __launch_bounds__(256) void dlstm_kernel(
    const float* __restrict__ inputs, const float* __restrict__ hx,
    const float* __restrict__ cx,     const float* __restrict__ memory,
    const float* __restrict__ w1,     const float* __restrict__ b1,
    const float* __restrict__ w2,     const float* __restrict__ b2,
    const float* __restrict__ w3,     const float* __restrict__ b3,
    const float* __restrict__ b_out,  float* __restrict__ out)
{
    __shared__ float xs[BATCH][IN_SZ];   // 33792 B
    __shared__ float Wl[IN_SZ][128];     // 33792 B (this block's 128 output cols)
    __shared__ float mem1[MEM_DIM];
    __shared__ float mem2[BOT_DIM];

    const int tid = threadIdx.x;
    const int n   = blockIdx.x >> 1;          // node
    const int r0  = (blockIdx.x & 1) * 32;    // which half of RU

    // ---- stage xs = concat(input, h) for this node, all batches ----
    for (int e = tid; e < BATCH * IN_SZ; e += 256) {
        int b = e / IN_SZ;
        int i = e - b * IN_SZ;
        float v;
        if (i < IN_PER_NODE)
            v = inputs[b * (NNODE * IN_PER_NODE) + n * IN_PER_NODE + i];
        else
            v = hx[(size_t)b * HID + n * RU + (i - IN_PER_NODE)];
        xs[b][i] = v;
    }

    // ---- hypernetwork bottleneck: mem2 = tanh(tanh(memory[n]@w1+b1)@w2+b2) ----
    if (tid < MEM_DIM) {
        float s = b1[tid];
        #pragma unroll
        for (int j = 0; j < MEM_DIM; ++j)
            s += memory[n * MEM_DIM + j] * w1[j * MEM_DIM + tid];
        mem1[tid] = tanhf(s);
    }
    __syncthreads();
    if (tid < BOT_DIM) {
        float s = b2[tid];
        #pragma unroll
        for (int j = 0; j < MEM_DIM; ++j)
            s += mem1[j] * w2[j * BOT_DIM + tid];
        mem2[tid] = tanhf(s);
    }
    __syncthreads();
    const float m0 = mem2[0], m1 = mem2[1], m2 = mem2[2], m3 = mem2[3];

    // ---- materialize this block's W columns: col c = g*32+rr -> o = g*64+r0+rr ----
    for (int e = tid; e < IN_SZ * 128; e += 256) {
        int i  = e >> 7;
        int c  = e & 127;
        int g  = c >> 5;
        int rr = c & 31;
        int j  = i * OUT_SZ + g * 64 + r0 + rr;
        Wl[i][c] = b3[j] + m0 * w3[j] + m1 * w3[W3_ROW + j]
                         + m2 * w3[2 * W3_ROW + j] + m3 * w3[3 * W3_ROW + j];
    }
    __syncthreads();

    // ---- matmul: each thread = (rr, 4 gates) x 16 batches ----
    const int rr = tid & 31;
    const int b0 = (tid >> 5) * 16;

    float acc[16][4];
    #pragma unroll
    for (int bb = 0; bb < 16; ++bb)
        acc[bb][0] = acc[bb][1] = acc[bb][2] = acc[bb][3] = 0.f;

    for (int i = 0; i < IN_SZ; ++i) {
        float w0 = Wl[i][rr];
        float w1v = Wl[i][32 + rr];
        float w2v = Wl[i][64 + rr];
        float w3v = Wl[i][96 + rr];
        #pragma unroll
        for (int bb = 0; bb < 16; ++bb) {
            float xv = xs[b0 + bb][i];
            acc[bb][0] += xv * w0;
            acc[bb][1] += xv * w1v;
            acc[bb][2] += xv * w2v;
            acc[bb][3] += xv * w3v;
        }
    }

    // ---- gates + LSTM cell epilogue ----
    const float bo0 = b_out[  0 + r0 + rr];
    const float bo1 = b_out[ 64 + r0 + rr];
    const float bo2 = b_out[128 + r0 + rr];
    const float bo3 = b_out[192 + r0 + rr];

    #pragma unroll
    for (int bb = 0; bb < 16; ++bb) {
        int b = b0 + bb;
        // reference: val = sigmoid(matmul) + b_out, THEN gate activations on val
        float vi = sigmoidf_(acc[bb][0]) + bo0;
        float vf = sigmoidf_(acc[bb][1]) + bo1;
        float vg = sigmoidf_(acc[bb][2]) + bo2;
        float vo = sigmoidf_(acc[bb][3]) + bo3;
        float it = sigmoidf_(vi);
        float ft = sigmoidf_(vf);
        float gt = tanhf(vg);
        float ot = sigmoidf_(vo);
        size_t idx = (size_t)b * HID + n * RU + r0 + rr;
        float c = cx[idx] * ft + it * gt;
        out[idx] = ot * tanhf(c);                 // hy
        out[(size_t)BATCH * HID + idx] = c;       // cy
    }
}

extern "C" void kernel_launch(void* const* d_in, const int* in_sizes, int n_in,
                              void* d_out, int out_size, void* d_ws, size_t ws_size,
                              hipStream_t stream) {
    const float* inputs = (const float*)d_in[0];
    const float* hx     = (const float*)d_in[1];
    const float* cx     = (const float*)d_in[2];
    const float* memory = (const float*)d_in[3];
    const float* w1     = (const float*)d_in[4];
    const float* b1     = (const float*)d_in[5];
    const float* w2     = (const float*)d_in[6];
    const float* b2     = (const float*)d_in[7];
    const float* w3     = (const float*)d_in[8];
    const float* b3     = (const float*)d_in[9];
    const float* b_out  = (const float*)d_in[10];
    float* out = (float*)d_out;

    dlstm_kernel<<<NNODE * 2, 256, 0, stream>>>(
        inputs, hx, cx, memory, w1, b1, w2, b2, w3, b3, b_out, out);
}